// Round 6
// baseline (290.375 us; speedup 1.0000x reference)
//
#include <hip/hip_runtime.h>

constexpr int NH = 8, DP = 63, D = 64, BATCH = 16, S = 2048;
constexpr float INVS = 1.0f / 2047.0f;
constexpr int NBLK = 128;   // 128 blocks x 256 threads, 80 KB LDS -> co-resident

// ---------------------------------------------------------------------------
// Device-scope grid barrier (no cooperative API).  Counter in d_ws, zeroed by
// hipMemsetAsync before launch.  Release-add flushes the writer XCD's L2;
// acquire-load invalidates the reader's -> cross-XCD visibility per G16.
// ---------------------------------------------------------------------------
__device__ __forceinline__ void gsync(unsigned int* bar, unsigned int target) {
    __syncthreads();
    if (threadIdx.x == 0) {
        __hip_atomic_fetch_add(bar, 1u, __ATOMIC_RELEASE, __HIP_MEMORY_SCOPE_AGENT);
        while (__hip_atomic_load(bar, __ATOMIC_ACQUIRE, __HIP_MEMORY_SCOPE_AGENT) < target)
            __builtin_amdgcn_s_sleep(2);
    }
    __syncthreads();
}

// ---------------------------------------------------------------------------
// Single fused kernel, grid 128 x 256, 9 manual grid barriers.
// ---------------------------------------------------------------------------
__global__ __launch_bounds__(256) void fused_all(
    const float* __restrict__ Z, const float* __restrict__ params,
    float* __restrict__ out, float* __restrict__ Gp, float* __restrict__ H,
    float* __restrict__ Gcur, float* __restrict__ Mt, float* __restrict__ Mf,
    unsigned int* bar) {
    __shared__ float4 sm4[5120];   // 80 KB
    const int bid = blockIdx.x, t = threadIdx.x;
    unsigned int tgt = NBLK;

    // ---------------- P0: Gram partials of input Z (256 rows/block) --------
    {
        float* ZN = (float*)(sm4 + 3072);            // [128][64] swizzled
        const int b = bid >> 3, oct = bid & 7;
        const int w = t >> 6, l = t & 63, qy = l >> 3, rx = l & 7;
        float g[8][8];
#pragma unroll
        for (int a = 0; a < 8; ++a)
#pragma unroll
            for (int bb = 0; bb < 8; ++bb) g[a][bb] = 0.f;

        for (int half = 0; half < 2; ++half) {
            const int rowbase = oct * 256 + half * 128;
#pragma unroll
            for (int k = 0; k < 8; ++k) {
                const int row = (t >> 4) + 16 * k, c4 = t & 15;
                const int grow = rowbase + row;
                float4 v = *(const float4*)&Z[((size_t)b * S + grow) * D + 4 * c4];
                if (grow == S - 1) v = make_float4(0.f, 0.f, 0.f, 0.f);  // mask last token
                *(float4*)&ZN[row * 64 + 4 * (c4 ^ ((row >> 3) & 15))] = v;
            }
            __syncthreads();
#pragma unroll 4
            for (int mi = 0; mi < 32; ++mi) {
                const int m = 32 * w + mi;
                const int f = (m >> 3) & 15;
                const float* rowp = &ZN[m * 64];
                float4 a0 = *(const float4*)&rowp[4 * (qy ^ f)];
                float4 a1 = *(const float4*)&rowp[4 * ((qy + 8) ^ f)];
                float4 b0 = *(const float4*)&rowp[4 * (rx ^ f)];
                float4 b1 = *(const float4*)&rowp[4 * ((rx + 8) ^ f)];
                float A[8]  = {a0.x, a0.y, a0.z, a0.w, a1.x, a1.y, a1.z, a1.w};
                float Bv[8] = {b0.x, b0.y, b0.z, b0.w, b1.x, b1.y, b1.z, b1.w};
#pragma unroll
                for (int a = 0; a < 8; ++a)
#pragma unroll
                    for (int bb = 0; bb < 8; ++bb) g[a][bb] += A[a] * Bv[bb];
            }
            __syncthreads();   // ZN reads done before restage / overlay
        }
        // per-wave partials -> sm4[0..4096) overlay, then reduce
        float* part = (float*)(sm4 + w * 1024);
#pragma unroll
        for (int a = 0; a < 8; ++a) {
            const int q = 4 * qy + (a & 3) + 32 * (a >> 2);
            *(float4*)&part[q * 64 + 4 * rx]      = make_float4(g[a][0], g[a][1], g[a][2], g[a][3]);
            *(float4*)&part[q * 64 + 32 + 4 * rx] = make_float4(g[a][4], g[a][5], g[a][6], g[a][7]);
        }
        __syncthreads();
        float4* gp4 = (float4*)(Gp + (size_t)(b * 8 + oct) * 4096);
#pragma unroll
        for (int k = 0; k < 4; ++k) {
            const int e4 = t + 256 * k;
            float4 s0 = sm4[e4], s1 = sm4[1024 + e4], s2 = sm4[2048 + e4], s3 = sm4[3072 + e4];
            gp4[e4] = make_float4(s0.x + s1.x + s2.x + s3.x, s0.y + s1.y + s2.y + s3.y,
                                  s0.z + s1.z + s2.z + s3.z, s0.w + s1.w + s2.w + s3.w);
        }
    }
    gsync(bar, tgt); tgt += NBLK;

    for (int layer = 0; layer < 4; ++layer) {
        // ---------------- P2: one head per block, H = Qf G Pf^T * INVS -----
        {
            float* Gs = (float*)sm4;      // [64][64] linear (symmetric)
            float* Pt = Gs + 4096;        // Pf^T [64][64] swizzled
            float* Qt = Pt + 4096;        // Qf^T [64][64] swizzled (Qt[q][p]=Qf[p][q])
            float* Tb = Qt + 4096;        // [64][64]
            const int b = bid >> 3, j = bid & 7;
            const float* P = params + ((size_t)(layer * NH + j) * 2) * (DP * DP);
            const float* Q = P + DP * DP;
            float4* Gs4 = (float4*)Gs;
            if (layer == 0) {
                const float4* Gp4 = (const float4*)Gp;
#pragma unroll
                for (int k = 0; k < 4; ++k) {
                    const int e4 = t + 256 * k;
                    float4 sum = make_float4(0.f, 0.f, 0.f, 0.f);
                    for (int p = 0; p < 8; ++p) {
                        float4 gg = Gp4[(size_t)(b * 8 + p) * 1024 + e4];
                        sum.x += gg.x; sum.y += gg.y; sum.z += gg.z; sum.w += gg.w;
                    }
                    Gs4[e4] = sum;
                }
            } else {
                const float4* Gc4 = (const float4*)(Gcur + (size_t)b * 4096);
#pragma unroll
                for (int k = 0; k < 4; ++k) Gs4[t + 256 * k] = Gc4[t + 256 * k];
            }
            {
                const int rr = t & 63, qtr = t >> 6;
#pragma unroll
                for (int k = 0; k < 16; ++k) {
                    const int i = qtr * 16 + k;
                    float pv = 0.f;
                    if (rr < DP && i < DP) pv = P[(size_t)i * DP + rr];        // Pf[i][rr]
                    else if (rr == DP && i == DP) pv = 1.f;                    // Pfull corner
                    Pt[rr * 64 + 4 * ((i >> 2) ^ (rr & 15)) + (i & 3)] = pv;
                    const float qv = (i < DP && rr < DP) ? Q[(size_t)i * DP + rr] : 0.f;  // Qf[i][rr]
                    Qt[rr * 64 + 4 * ((i >> 2) ^ (rr & 15)) + (i & 3)] = qv;
                }
            }
            __syncthreads();
            const int ty = t >> 4, tx = t & 15;
            // mm1: T[q][i] = sum_r G[r][q] * Pf^T[r][i]   (G symmetric)
            float acc[4][4] = {};
#pragma unroll 4
            for (int r = 0; r < 64; ++r) {
                float4 av = *(const float4*)&Gs[r * 64 + 4 * ty];
                float4 bv = *(const float4*)&Pt[r * 64 + 4 * (tx ^ (r & 15))];
                float A[4] = {av.x, av.y, av.z, av.w}, Bb[4] = {bv.x, bv.y, bv.z, bv.w};
#pragma unroll
                for (int a = 0; a < 4; ++a)
#pragma unroll
                    for (int c = 0; c < 4; ++c) acc[a][c] += A[a] * Bb[c];
            }
#pragma unroll
            for (int a = 0; a < 4; ++a)
                *(float4*)&Tb[(4 * ty + a) * 64 + 4 * tx] =
                    make_float4(acc[a][0], acc[a][1], acc[a][2], acc[a][3]);
            __syncthreads();
            // mm2: H[p][i] = sum_q Qf[p][q] * T[q][i]
            float acc2[4][4] = {};
#pragma unroll 4
            for (int q = 0; q < 64; ++q) {
                float4 av = *(const float4*)&Qt[q * 64 + 4 * (ty ^ (q & 15))];
                float4 bv = *(const float4*)&Tb[q * 64 + 4 * tx];
                float A[4] = {av.x, av.y, av.z, av.w}, Bb[4] = {bv.x, bv.y, bv.z, bv.w};
#pragma unroll
                for (int a = 0; a < 4; ++a)
#pragma unroll
                    for (int c = 0; c < 4; ++c) acc2[a][c] += A[a] * Bb[c];
            }
            float* Hb = H + (size_t)(b * NH + j) * 4096;
#pragma unroll
            for (int a = 0; a < 4; ++a)
                *(float4*)&Hb[(4 * ty + a) * 64 + 4 * tx] =
                    make_float4(acc2[a][0] * INVS, acc2[a][1] * INVS,
                                acc2[a][2] * INVS, acc2[a][3] * INVS);
        }
        gsync(bar, tgt); tgt += NBLK;

        // ---------------- P3: per-batch update (16 of 128 blocks) ----------
        if (bid < 16) {
            const int b = bid;
            float* Ws = (float*)sm4;       // W = I + sum H
            float* As = Ws + 4096;         // Gcur (symmetric)
            float* Ts = As + 4096;         // T = Gcur*W
            float* Ms = Ts + 4096;         // Mt_old (= M^T)
            float4* Ws4 = (float4*)Ws; float4* As4 = (float4*)As; float4* Ms4 = (float4*)Ms;
#pragma unroll
            for (int k = 0; k < 4; ++k) {
                const int e4 = t + 256 * k;
                float iv[4];
#pragma unroll
                for (int c = 0; c < 4; ++c) {
                    const int e = 4 * e4 + c;
                    iv[c] = ((e >> 6) == (e & 63)) ? 1.f : 0.f;
                }
                float4 w = make_float4(iv[0], iv[1], iv[2], iv[3]);
                const float4* H4 = (const float4*)H;
                for (int j = 0; j < 8; ++j) {
                    float4 h = H4[(size_t)(b * 8 + j) * 1024 + e4];
                    w.x += h.x; w.y += h.y; w.z += h.z; w.w += h.w;
                }
                Ws4[e4] = w;
                if (layer == 0) {
                    const float4* Gp4 = (const float4*)Gp;
                    float4 sum = make_float4(0.f, 0.f, 0.f, 0.f);
                    for (int p = 0; p < 8; ++p) {
                        float4 gg = Gp4[(size_t)(b * 8 + p) * 1024 + e4];
                        sum.x += gg.x; sum.y += gg.y; sum.z += gg.z; sum.w += gg.w;
                    }
                    As4[e4] = sum;
                    Ms4[e4] = make_float4(iv[0], iv[1], iv[2], iv[3]);   // M^T = I
                } else {
                    As4[e4] = ((const float4*)(Gcur + (size_t)b * 4096))[e4];
                    Ms4[e4] = ((const float4*)(Mt + (size_t)b * 4096))[e4];
                }
            }
            __syncthreads();
            const int ty = t >> 4, tx = t & 15;
            if (layer < 3) {
                // T[q][i] = sum_r G[r][q] * W[r][i]   (G symmetric)
                float acc[4][4] = {};
#pragma unroll 4
                for (int r = 0; r < 64; ++r) {
                    float4 av = *(const float4*)&As[r * 64 + 4 * ty];
                    float4 bv = *(const float4*)&Ws[r * 64 + 4 * tx];
                    float A[4] = {av.x, av.y, av.z, av.w}, Bb[4] = {bv.x, bv.y, bv.z, bv.w};
#pragma unroll
                    for (int a = 0; a < 4; ++a)
#pragma unroll
                        for (int c = 0; c < 4; ++c) acc[a][c] += A[a] * Bb[c];
                }
#pragma unroll
                for (int a = 0; a < 4; ++a)
                    *(float4*)&Ts[(4 * ty + a) * 64 + 4 * tx] =
                        make_float4(acc[a][0], acc[a][1], acc[a][2], acc[a][3]);
                __syncthreads();
                // Gnext[q][i] = sum_p W[p][q] T[p][i];  Mt_new[i][q] = sum_p W[p][i] Mt_old[p][q]
                float accG[4][4] = {}, accM[4][4] = {};
#pragma unroll 4
                for (int p = 0; p < 64; ++p) {
                    float4 av = *(const float4*)&Ws[p * 64 + 4 * ty];
                    float4 bv = *(const float4*)&Ts[p * 64 + 4 * tx];
                    float4 cv = *(const float4*)&Ms[p * 64 + 4 * tx];
                    float A[4] = {av.x, av.y, av.z, av.w};
                    float Bb[4] = {bv.x, bv.y, bv.z, bv.w};
                    float Cc[4] = {cv.x, cv.y, cv.z, cv.w};
#pragma unroll
                    for (int a = 0; a < 4; ++a)
#pragma unroll
                        for (int c = 0; c < 4; ++c) {
                            accG[a][c] += A[a] * Bb[c];
                            accM[a][c] += A[a] * Cc[c];
                        }
                }
                float* Gout = Gcur + (size_t)b * 4096;
                float* Mout = Mt + (size_t)b * 4096;
#pragma unroll
                for (int a = 0; a < 4; ++a) {
                    *(float4*)&Gout[(4 * ty + a) * 64 + 4 * tx] =
                        make_float4(accG[a][0], accG[a][1], accG[a][2], accG[a][3]);
                    *(float4*)&Mout[(4 * ty + a) * 64 + 4 * tx] =
                        make_float4(accM[a][0], accM[a][1], accM[a][2], accM[a][3]);
                }
            } else {
                // final: Mf[q][i] = sum_p Mt_old[p][q] * W[p][i]
                float accM[4][4] = {};
#pragma unroll 4
                for (int p = 0; p < 64; ++p) {
                    float4 av = *(const float4*)&Ms[p * 64 + 4 * ty];
                    float4 bv = *(const float4*)&Ws[p * 64 + 4 * tx];
                    float A[4] = {av.x, av.y, av.z, av.w}, Bb[4] = {bv.x, bv.y, bv.z, bv.w};
#pragma unroll
                    for (int a = 0; a < 4; ++a)
#pragma unroll
                        for (int c = 0; c < 4; ++c) accM[a][c] += A[a] * Bb[c];
                }
                float* Mout = Mf + (size_t)b * 4096;
#pragma unroll
                for (int a = 0; a < 4; ++a)
                    *(float4*)&Mout[(4 * ty + a) * 64 + 4 * tx] =
                        make_float4(accM[a][0], accM[a][1], accM[a][2], accM[a][3]);
            }
        }
        gsync(bar, tgt); tgt += NBLK;
    }

    // ---------------- P4: out = Z @ Mf[b]  (256 rows/block) ----------------
    {
        float* ZT = (float*)sm4;            // Z^T [64][128] swizzled
        float* Ws = (float*)(sm4 + 2048);   // Mf [64][64] linear
        const int b = bid >> 3, oct = bid & 7;
        const int ny = t & 15, ix = t >> 4;
#pragma unroll
        for (int k = 0; k < 4; ++k)
            ((float4*)Ws)[t + 256 * k] = ((const float4*)(Mf + (size_t)b * 4096))[t + 256 * k];
        for (int half = 0; half < 2; ++half) {
            const size_t zbase = ((size_t)b * S + oct * 256 + half * 128) * D;
            __syncthreads();   // previous ZT reads done; Ws ready (first iter via next sync)
#pragma unroll
            for (int k = 0; k < 8; ++k) {
                const int row = (t >> 4) + 16 * k, c4 = t & 15;
                float4 v = *(const float4*)&Z[zbase + (size_t)row * D + 4 * c4];
                float vv[4] = {v.x, v.y, v.z, v.w};
#pragma unroll
                for (int c = 0; c < 4; ++c)
                    ZT[(4 * c4 + c) * 128 + 4 * ((row >> 2) ^ c4) + (row & 3)] = vv[c];
            }
            __syncthreads();
            float acc[8][4] = {};
#pragma unroll 4
            for (int p = 0; p < 64; ++p) {
                const int f = p >> 2;
                const float* zp = &ZT[p * 128];
                float4 a0 = *(const float4*)&zp[4 * (ny ^ f)];
                float4 a1 = *(const float4*)&zp[4 * ((ny + 16) ^ f)];
                float4 wv = *(const float4*)&Ws[p * 64 + 4 * ix];
                float A[8] = {a0.x, a0.y, a0.z, a0.w, a1.x, a1.y, a1.z, a1.w};
                float Wv[4] = {wv.x, wv.y, wv.z, wv.w};
#pragma unroll
                for (int a = 0; a < 8; ++a)
#pragma unroll
                    for (int c = 0; c < 4; ++c) acc[a][c] += A[a] * Wv[c];
            }
#pragma unroll
            for (int a = 0; a < 8; ++a) {
                const int n = 4 * ny + (a & 3) + 64 * (a >> 2);
                *(float4*)&out[zbase + (size_t)n * D + 4 * ix] =
                    make_float4(acc[a][0], acc[a][1], acc[a][2], acc[a][3]);
            }
        }
    }
}

// ---------------------------------------------------------------------------
extern "C" void kernel_launch(void* const* d_in, const int* in_sizes, int n_in,
                              void* d_out, int out_size, void* d_ws, size_t ws_size,
                              hipStream_t stream) {
    const float* Z        = (const float*)d_in[0];
    const float* allparam = (const float*)d_in[1];
    float* out = (float*)d_out;

    float* Gp = (float*)d_ws;                       // 128*4096 floats = 2 MB
    float* H  = Gp + (size_t)NBLK * 4096;           // 16*8*4096      = 2 MB
    float* Gc = H + (size_t)BATCH * NH * 4096;      // 16*4096
    float* Mt = Gc + (size_t)BATCH * 4096;          // 16*4096
    float* Mf = Mt + (size_t)BATCH * 4096;          // 16*4096
    unsigned int* bar = (unsigned int*)(Mf + (size_t)BATCH * 4096);

    hipMemsetAsync(bar, 0, 64, stream);   // zero grid-barrier counter (capturable)
    fused_all<<<NBLK, 256, 0, stream>>>(Z, allparam, out, Gp, H, Gc, Mt, Mf, bar);
}

// Round 10
// 267.212 us; speedup vs baseline: 1.0867x; 1.0867x over previous
//
#include <hip/hip_runtime.h>

constexpr int NH = 8, DP = 63, D = 64, BATCH = 16, S = 2048;
constexpr float INVS = 1.0f / 2047.0f;
constexpr int NBLK = 128;   // 128 blocks x 256 threads, 80 KB LDS -> co-resident

// ---------------------------------------------------------------------------
// Device-scope grid barrier (no cooperative API).  Counter in d_ws, zeroed by
// hipMemsetAsync before launch.  KEY: spin on RELAXED atomic loads (no cache
// maintenance per iteration); exactly ONE release fence before the add and ONE
// acquire fence after the spin (this is how HIP's own grid.sync is built).
// Round-6's ACQUIRE-per-iteration spin caused an L2-invalidate storm (~24 us
// per barrier, VALUBusy 4.4%).
// ---------------------------------------------------------------------------
__device__ __forceinline__ void gsync(unsigned int* bar, unsigned int target) {
    __syncthreads();
    if (threadIdx.x == 0) {
        __builtin_amdgcn_fence(__ATOMIC_RELEASE, "agent");   // flush our writes
        __hip_atomic_fetch_add(bar, 1u, __ATOMIC_RELAXED, __HIP_MEMORY_SCOPE_AGENT);
        while (__hip_atomic_load(bar, __ATOMIC_RELAXED, __HIP_MEMORY_SCOPE_AGENT) < target)
            __builtin_amdgcn_s_sleep(2);
        __builtin_amdgcn_fence(__ATOMIC_ACQUIRE, "agent");   // invalidate stale caches
    }
    __syncthreads();
}

// ---------------------------------------------------------------------------
// Single fused kernel, grid 128 x 256, 9 manual grid barriers.
// ---------------------------------------------------------------------------
__global__ __launch_bounds__(256) void fused_all(
    const float* __restrict__ Z, const float* __restrict__ params,
    float* __restrict__ out, float* __restrict__ Gp, float* __restrict__ H,
    float* __restrict__ Gcur, float* __restrict__ Mt, float* __restrict__ Mf,
    unsigned int* bar) {
    __shared__ float4 sm4[5120];   // 80 KB
    const int bid = blockIdx.x, t = threadIdx.x;
    unsigned int tgt = NBLK;

    // ---------------- P0: Gram partials of input Z (256 rows/block) --------
    {
        float* ZN = (float*)(sm4 + 3072);            // [128][64] swizzled
        const int b = bid >> 3, oct = bid & 7;
        const int w = t >> 6, l = t & 63, qy = l >> 3, rx = l & 7;
        float g[8][8];
#pragma unroll
        for (int a = 0; a < 8; ++a)
#pragma unroll
            for (int bb = 0; bb < 8; ++bb) g[a][bb] = 0.f;

        for (int half = 0; half < 2; ++half) {
            const int rowbase = oct * 256 + half * 128;
#pragma unroll
            for (int k = 0; k < 8; ++k) {
                const int row = (t >> 4) + 16 * k, c4 = t & 15;
                const int grow = rowbase + row;
                float4 v = *(const float4*)&Z[((size_t)b * S + grow) * D + 4 * c4];
                if (grow == S - 1) v = make_float4(0.f, 0.f, 0.f, 0.f);  // mask last token
                *(float4*)&ZN[row * 64 + 4 * (c4 ^ ((row >> 3) & 15))] = v;
            }
            __syncthreads();
#pragma unroll 4
            for (int mi = 0; mi < 32; ++mi) {
                const int m = 32 * w + mi;
                const int f = (m >> 3) & 15;
                const float* rowp = &ZN[m * 64];
                float4 a0 = *(const float4*)&rowp[4 * (qy ^ f)];
                float4 a1 = *(const float4*)&rowp[4 * ((qy + 8) ^ f)];
                float4 b0 = *(const float4*)&rowp[4 * (rx ^ f)];
                float4 b1 = *(const float4*)&rowp[4 * ((rx + 8) ^ f)];
                float A[8]  = {a0.x, a0.y, a0.z, a0.w, a1.x, a1.y, a1.z, a1.w};
                float Bv[8] = {b0.x, b0.y, b0.z, b0.w, b1.x, b1.y, b1.z, b1.w};
#pragma unroll
                for (int a = 0; a < 8; ++a)
#pragma unroll
                    for (int bb = 0; bb < 8; ++bb) g[a][bb] += A[a] * Bv[bb];
            }
            __syncthreads();   // ZN reads done before restage / overlay
        }
        // per-wave partials -> sm4[0..4096) overlay, then reduce
        float* part = (float*)(sm4 + w * 1024);
#pragma unroll
        for (int a = 0; a < 8; ++a) {
            const int q = 4 * qy + (a & 3) + 32 * (a >> 2);
            *(float4*)&part[q * 64 + 4 * rx]      = make_float4(g[a][0], g[a][1], g[a][2], g[a][3]);
            *(float4*)&part[q * 64 + 32 + 4 * rx] = make_float4(g[a][4], g[a][5], g[a][6], g[a][7]);
        }
        __syncthreads();
        float4* gp4 = (float4*)(Gp + (size_t)(b * 8 + oct) * 4096);
#pragma unroll
        for (int k = 0; k < 4; ++k) {
            const int e4 = t + 256 * k;
            float4 s0 = sm4[e4], s1 = sm4[1024 + e4], s2 = sm4[2048 + e4], s3 = sm4[3072 + e4];
            gp4[e4] = make_float4(s0.x + s1.x + s2.x + s3.x, s0.y + s1.y + s2.y + s3.y,
                                  s0.z + s1.z + s2.z + s3.z, s0.w + s1.w + s2.w + s3.w);
        }
    }
    gsync(bar, tgt); tgt += NBLK;

    for (int layer = 0; layer < 4; ++layer) {
        // ---------------- P2: one head per block, H = Qf G Pf^T * INVS -----
        {
            float* Gs = (float*)sm4;      // [64][64] linear (symmetric)
            float* Pt = Gs + 4096;        // Pf^T [64][64] swizzled
            float* Qt = Pt + 4096;        // Qf^T [64][64] swizzled (Qt[q][p]=Qf[p][q])
            float* Tb = Qt + 4096;        // [64][64]
            const int b = bid >> 3, j = bid & 7;
            const float* P = params + ((size_t)(layer * NH + j) * 2) * (DP * DP);
            const float* Q = P + DP * DP;
            float4* Gs4 = (float4*)Gs;
            if (layer == 0) {
                const float4* Gp4 = (const float4*)Gp;
#pragma unroll
                for (int k = 0; k < 4; ++k) {
                    const int e4 = t + 256 * k;
                    float4 sum = make_float4(0.f, 0.f, 0.f, 0.f);
                    for (int p = 0; p < 8; ++p) {
                        float4 gg = Gp4[(size_t)(b * 8 + p) * 1024 + e4];
                        sum.x += gg.x; sum.y += gg.y; sum.z += gg.z; sum.w += gg.w;
                    }
                    Gs4[e4] = sum;
                }
            } else {
                const float4* Gc4 = (const float4*)(Gcur + (size_t)b * 4096);
#pragma unroll
                for (int k = 0; k < 4; ++k) Gs4[t + 256 * k] = Gc4[t + 256 * k];
            }
            {
                const int rr = t & 63, qtr = t >> 6;
#pragma unroll
                for (int k = 0; k < 16; ++k) {
                    const int i = qtr * 16 + k;
                    float pv = 0.f;
                    if (rr < DP && i < DP) pv = P[(size_t)i * DP + rr];        // Pf[i][rr]
                    else if (rr == DP && i == DP) pv = 1.f;                    // Pfull corner
                    Pt[rr * 64 + 4 * ((i >> 2) ^ (rr & 15)) + (i & 3)] = pv;
                    const float qv = (i < DP && rr < DP) ? Q[(size_t)i * DP + rr] : 0.f;  // Qf[i][rr]
                    Qt[rr * 64 + 4 * ((i >> 2) ^ (rr & 15)) + (i & 3)] = qv;
                }
            }
            __syncthreads();
            const int ty = t >> 4, tx = t & 15;
            // mm1: T[q][i] = sum_r G[r][q] * Pf^T[r][i]   (G symmetric)
            float acc[4][4] = {};
#pragma unroll 4
            for (int r = 0; r < 64; ++r) {
                float4 av = *(const float4*)&Gs[r * 64 + 4 * ty];
                float4 bv = *(const float4*)&Pt[r * 64 + 4 * (tx ^ (r & 15))];
                float A[4] = {av.x, av.y, av.z, av.w}, Bb[4] = {bv.x, bv.y, bv.z, bv.w};
#pragma unroll
                for (int a = 0; a < 4; ++a)
#pragma unroll
                    for (int c = 0; c < 4; ++c) acc[a][c] += A[a] * Bb[c];
            }
#pragma unroll
            for (int a = 0; a < 4; ++a)
                *(float4*)&Tb[(4 * ty + a) * 64 + 4 * tx] =
                    make_float4(acc[a][0], acc[a][1], acc[a][2], acc[a][3]);
            __syncthreads();
            // mm2: H[p][i] = sum_q Qf[p][q] * T[q][i]
            float acc2[4][4] = {};
#pragma unroll 4
            for (int q = 0; q < 64; ++q) {
                float4 av = *(const float4*)&Qt[q * 64 + 4 * (ty ^ (q & 15))];
                float4 bv = *(const float4*)&Tb[q * 64 + 4 * tx];
                float A[4] = {av.x, av.y, av.z, av.w}, Bb[4] = {bv.x, bv.y, bv.z, bv.w};
#pragma unroll
                for (int a = 0; a < 4; ++a)
#pragma unroll
                    for (int c = 0; c < 4; ++c) acc2[a][c] += A[a] * Bb[c];
            }
            float* Hb = H + (size_t)(b * NH + j) * 4096;
#pragma unroll
            for (int a = 0; a < 4; ++a)
                *(float4*)&Hb[(4 * ty + a) * 64 + 4 * tx] =
                    make_float4(acc2[a][0] * INVS, acc2[a][1] * INVS,
                                acc2[a][2] * INVS, acc2[a][3] * INVS);
        }
        gsync(bar, tgt); tgt += NBLK;

        // ---------------- P3: per-batch update (16 of 128 blocks) ----------
        if (bid < 16) {
            const int b = bid;
            float* Ws = (float*)sm4;       // W = I + sum H
            float* As = Ws + 4096;         // Gcur (symmetric)
            float* Ts = As + 4096;         // T = Gcur*W
            float* Ms = Ts + 4096;         // Mt_old (= M^T)
            float4* Ws4 = (float4*)Ws; float4* As4 = (float4*)As; float4* Ms4 = (float4*)Ms;
#pragma unroll
            for (int k = 0; k < 4; ++k) {
                const int e4 = t + 256 * k;
                float iv[4];
#pragma unroll
                for (int c = 0; c < 4; ++c) {
                    const int e = 4 * e4 + c;
                    iv[c] = ((e >> 6) == (e & 63)) ? 1.f : 0.f;
                }
                float4 w = make_float4(iv[0], iv[1], iv[2], iv[3]);
                const float4* H4 = (const float4*)H;
                for (int j = 0; j < 8; ++j) {
                    float4 h = H4[(size_t)(b * 8 + j) * 1024 + e4];
                    w.x += h.x; w.y += h.y; w.z += h.z; w.w += h.w;
                }
                Ws4[e4] = w;
                if (layer == 0) {
                    const float4* Gp4 = (const float4*)Gp;
                    float4 sum = make_float4(0.f, 0.f, 0.f, 0.f);
                    for (int p = 0; p < 8; ++p) {
                        float4 gg = Gp4[(size_t)(b * 8 + p) * 1024 + e4];
                        sum.x += gg.x; sum.y += gg.y; sum.z += gg.z; sum.w += gg.w;
                    }
                    As4[e4] = sum;
                    Ms4[e4] = make_float4(iv[0], iv[1], iv[2], iv[3]);   // M^T = I
                } else {
                    As4[e4] = ((const float4*)(Gcur + (size_t)b * 4096))[e4];
                    Ms4[e4] = ((const float4*)(Mt + (size_t)b * 4096))[e4];
                }
            }
            __syncthreads();
            const int ty = t >> 4, tx = t & 15;
            if (layer < 3) {
                // T[q][i] = sum_r G[r][q] * W[r][i]   (G symmetric)
                float acc[4][4] = {};
#pragma unroll 4
                for (int r = 0; r < 64; ++r) {
                    float4 av = *(const float4*)&As[r * 64 + 4 * ty];
                    float4 bv = *(const float4*)&Ws[r * 64 + 4 * tx];
                    float A[4] = {av.x, av.y, av.z, av.w}, Bb[4] = {bv.x, bv.y, bv.z, bv.w};
#pragma unroll
                    for (int a = 0; a < 4; ++a)
#pragma unroll
                        for (int c = 0; c < 4; ++c) acc[a][c] += A[a] * Bb[c];
                }
#pragma unroll
                for (int a = 0; a < 4; ++a)
                    *(float4*)&Ts[(4 * ty + a) * 64 + 4 * tx] =
                        make_float4(acc[a][0], acc[a][1], acc[a][2], acc[a][3]);
                __syncthreads();
                // Gnext[q][i] = sum_p W[p][q] T[p][i];  Mt_new[i][q] = sum_p W[p][i] Mt_old[p][q]
                float accG[4][4] = {}, accM[4][4] = {};
#pragma unroll 4
                for (int p = 0; p < 64; ++p) {
                    float4 av = *(const float4*)&Ws[p * 64 + 4 * ty];
                    float4 bv = *(const float4*)&Ts[p * 64 + 4 * tx];
                    float4 cv = *(const float4*)&Ms[p * 64 + 4 * tx];
                    float A[4] = {av.x, av.y, av.z, av.w};
                    float Bb[4] = {bv.x, bv.y, bv.z, bv.w};
                    float Cc[4] = {cv.x, cv.y, cv.z, cv.w};
#pragma unroll
                    for (int a = 0; a < 4; ++a)
#pragma unroll
                        for (int c = 0; c < 4; ++c) {
                            accG[a][c] += A[a] * Bb[c];
                            accM[a][c] += A[a] * Cc[c];
                        }
                }
                float* Gout = Gcur + (size_t)b * 4096;
                float* Mout = Mt + (size_t)b * 4096;
#pragma unroll
                for (int a = 0; a < 4; ++a) {
                    *(float4*)&Gout[(4 * ty + a) * 64 + 4 * tx] =
                        make_float4(accG[a][0], accG[a][1], accG[a][2], accG[a][3]);
                    *(float4*)&Mout[(4 * ty + a) * 64 + 4 * tx] =
                        make_float4(accM[a][0], accM[a][1], accM[a][2], accM[a][3]);
                }
            } else {
                // final: Mf[q][i] = sum_p Mt_old[p][q] * W[p][i]
                float accM[4][4] = {};
#pragma unroll 4
                for (int p = 0; p < 64; ++p) {
                    float4 av = *(const float4*)&Ms[p * 64 + 4 * ty];
                    float4 bv = *(const float4*)&Ws[p * 64 + 4 * tx];
                    float A[4] = {av.x, av.y, av.z, av.w}, Bb[4] = {bv.x, bv.y, bv.z, bv.w};
#pragma unroll
                    for (int a = 0; a < 4; ++a)
#pragma unroll
                        for (int c = 0; c < 4; ++c) accM[a][c] += A[a] * Bb[c];
                }
                float* Mout = Mf + (size_t)b * 4096;
#pragma unroll
                for (int a = 0; a < 4; ++a)
                    *(float4*)&Mout[(4 * ty + a) * 64 + 4 * tx] =
                        make_float4(accM[a][0], accM[a][1], accM[a][2], accM[a][3]);
            }
        }
        gsync(bar, tgt); tgt += NBLK;
    }

    // ---------------- P4: out = Z @ Mf[b]  (256 rows/block) ----------------
    {
        float* ZT = (float*)sm4;            // Z^T [64][128] swizzled
        float* Ws = (float*)(sm4 + 2048);   // Mf [64][64] linear
        const int b = bid >> 3, oct = bid & 7;
        const int ny = t & 15, ix = t >> 4;
#pragma unroll
        for (int k = 0; k < 4; ++k)
            ((float4*)Ws)[t + 256 * k] = ((const float4*)(Mf + (size_t)b * 4096))[t + 256 * k];
        for (int half = 0; half < 2; ++half) {
            const size_t zbase = ((size_t)b * S + oct * 256 + half * 128) * D;
            __syncthreads();   // previous ZT reads done; Ws ready
#pragma unroll
            for (int k = 0; k < 8; ++k) {
                const int row = (t >> 4) + 16 * k, c4 = t & 15;
                float4 v = *(const float4*)&Z[zbase + (size_t)row * D + 4 * c4];
                float vv[4] = {v.x, v.y, v.z, v.w};
#pragma unroll
                for (int c = 0; c < 4; ++c)
                    ZT[(4 * c4 + c) * 128 + 4 * ((row >> 2) ^ c4) + (row & 3)] = vv[c];
            }
            __syncthreads();
            float acc[8][4] = {};
#pragma unroll 4
            for (int p = 0; p < 64; ++p) {
                const int f = p >> 2;
                const float* zp = &ZT[p * 128];
                float4 a0 = *(const float4*)&zp[4 * (ny ^ f)];
                float4 a1 = *(const float4*)&zp[4 * ((ny + 16) ^ f)];
                float4 wv = *(const float4*)&Ws[p * 64 + 4 * ix];
                float A[8] = {a0.x, a0.y, a0.z, a0.w, a1.x, a1.y, a1.z, a1.w};
                float Wv[4] = {wv.x, wv.y, wv.z, wv.w};
#pragma unroll
                for (int a = 0; a < 8; ++a)
#pragma unroll
                    for (int c = 0; c < 4; ++c) acc[a][c] += A[a] * Wv[c];
            }
#pragma unroll
            for (int a = 0; a < 8; ++a) {
                const int n = 4 * ny + (a & 3) + 64 * (a >> 2);
                *(float4*)&out[zbase + (size_t)n * D + 4 * ix] =
                    make_float4(acc[a][0], acc[a][1], acc[a][2], acc[a][3]);
            }
        }
    }
}

// ---------------------------------------------------------------------------
extern "C" void kernel_launch(void* const* d_in, const int* in_sizes, int n_in,
                              void* d_out, int out_size, void* d_ws, size_t ws_size,
                              hipStream_t stream) {
    const float* Z        = (const float*)d_in[0];
    const float* allparam = (const float*)d_in[1];
    float* out = (float*)d_out;

    float* Gp = (float*)d_ws;                       // 128*4096 floats = 2 MB
    float* H  = Gp + (size_t)NBLK * 4096;           // 16*8*4096      = 2 MB
    float* Gc = H + (size_t)BATCH * NH * 4096;      // 16*4096
    float* Mt = Gc + (size_t)BATCH * 4096;          // 16*4096
    float* Mf = Mt + (size_t)BATCH * 4096;          // 16*4096
    unsigned int* bar = (unsigned int*)(Mf + (size_t)BATCH * 4096);

    hipMemsetAsync(bar, 0, 64, stream);   // zero grid-barrier counter (capturable)
    fused_all<<<NBLK, 256, 0, stream>>>(Z, allparam, out, Gp, H, Gc, Mt, Mf, bar);
}

// Round 13
// 221.597 us; speedup vs baseline: 1.3104x; 1.2058x over previous
//
#include <hip/hip_runtime.h>

constexpr int NH = 8, DP = 63, D = 64, BATCH = 16, S = 2048;
constexpr float INVS = 1.0f / 2047.0f;
constexpr int NBLK = 128;   // 128 blocks x 256 threads, 80 KB LDS, 1 block/CU

// ---------------------------------------------------------------------------
// Device-scope grid barrier.  Relaxed spin + single release/acquire fence
// (round-10 validated).  Now only 5 per kernel, and phases dirty ~16 KB/block
// instead of MBs, so the release L2-writeback is cheap.
// ---------------------------------------------------------------------------
__device__ __forceinline__ void gsync(unsigned int* bar, unsigned int target) {
    __syncthreads();
    if (threadIdx.x == 0) {
        __builtin_amdgcn_fence(__ATOMIC_RELEASE, "agent");
        __hip_atomic_fetch_add(bar, 1u, __ATOMIC_RELAXED, __HIP_MEMORY_SCOPE_AGENT);
        while (__hip_atomic_load(bar, __ATOMIC_RELAXED, __HIP_MEMORY_SCOPE_AGENT) < target)
            __builtin_amdgcn_s_sleep(2);
        __builtin_amdgcn_fence(__ATOMIC_ACQUIRE, "agent");
    }
    __syncthreads();
}

// ---------------------------------------------------------------------------
// Single fused kernel, grid 128 x 256, 5 grid barriers.
// Block (b, j): gram partial for oct=j; head j of batch b; REDUNDANT per-batch
// update (G, M^T persist in LDS); apply rows oct=j of batch b.
// ---------------------------------------------------------------------------
__global__ __launch_bounds__(256) void fused_all(
    const float* __restrict__ Z, const float* __restrict__ params,
    float* __restrict__ out, float* __restrict__ Gp, float* __restrict__ H,
    unsigned int* bar) {
    __shared__ float4 sm4[5120];                  // 80 KB
    float* As = (float*)sm4;                      // G[b] persistent     (16 KB)
    float* Ms = (float*)(sm4 + 1024);             // M^T persistent      (16 KB)
    float* Pt = (float*)(sm4 + 2048);             // Pf^T slot / W slot  (16 KB)
    float* Qt = (float*)(sm4 + 3072);             // Qf^T slot           (16 KB)
    float* Tb = (float*)(sm4 + 4096);             // T slot / Mf slot    (16 KB)
    const int bid = blockIdx.x, t = threadIdx.x;
    const int b = bid >> 3, j = bid & 7;
    unsigned int tgt = NBLK;

    // ---------------- P0: Gram partial of input Z (256 rows, oct=j) --------
    {
        float* ZN = (float*)(sm4 + 3072);         // [128][64] swizzled (Qt+Tb)
        const int w = t >> 6, l = t & 63, qy = l >> 3, rx = l & 7;
        float g[8][8];
#pragma unroll
        for (int a = 0; a < 8; ++a)
#pragma unroll
            for (int bb = 0; bb < 8; ++bb) g[a][bb] = 0.f;

        for (int half = 0; half < 2; ++half) {
            const int rowbase = j * 256 + half * 128;
#pragma unroll
            for (int k = 0; k < 8; ++k) {
                const int row = (t >> 4) + 16 * k, c4 = t & 15;
                const int grow = rowbase + row;
                float4 v = *(const float4*)&Z[((size_t)b * S + grow) * D + 4 * c4];
                if (grow == S - 1) v = make_float4(0.f, 0.f, 0.f, 0.f);  // mask last token
                *(float4*)&ZN[row * 64 + 4 * (c4 ^ ((row >> 3) & 15))] = v;
            }
            __syncthreads();
#pragma unroll 4
            for (int mi = 0; mi < 32; ++mi) {
                const int m = 32 * w + mi;
                const int f = (m >> 3) & 15;
                const float* rowp = &ZN[m * 64];
                float4 a0 = *(const float4*)&rowp[4 * (qy ^ f)];
                float4 a1 = *(const float4*)&rowp[4 * ((qy + 8) ^ f)];
                float4 b0 = *(const float4*)&rowp[4 * (rx ^ f)];
                float4 b1 = *(const float4*)&rowp[4 * ((rx + 8) ^ f)];
                float A[8]  = {a0.x, a0.y, a0.z, a0.w, a1.x, a1.y, a1.z, a1.w};
                float Bv[8] = {b0.x, b0.y, b0.z, b0.w, b1.x, b1.y, b1.z, b1.w};
#pragma unroll
                for (int a = 0; a < 8; ++a)
#pragma unroll
                    for (int bb = 0; bb < 8; ++bb) g[a][bb] += A[a] * Bv[bb];
            }
            __syncthreads();   // ZN reads done before restage / overlay
        }
        float* part = (float*)(sm4 + w * 1024);
#pragma unroll
        for (int a = 0; a < 8; ++a) {
            const int q = 4 * qy + (a & 3) + 32 * (a >> 2);
            *(float4*)&part[q * 64 + 4 * rx]      = make_float4(g[a][0], g[a][1], g[a][2], g[a][3]);
            *(float4*)&part[q * 64 + 32 + 4 * rx] = make_float4(g[a][4], g[a][5], g[a][6], g[a][7]);
        }
        __syncthreads();
        float4* gp4 = (float4*)(Gp + (size_t)(b * 8 + j) * 4096);
#pragma unroll
        for (int k = 0; k < 4; ++k) {
            const int e4 = t + 256 * k;
            float4 s0 = sm4[e4], s1 = sm4[1024 + e4], s2 = sm4[2048 + e4], s3 = sm4[3072 + e4];
            gp4[e4] = make_float4(s0.x + s1.x + s2.x + s3.x, s0.y + s1.y + s2.y + s3.y,
                                  s0.z + s1.z + s2.z + s3.z, s0.w + s1.w + s2.w + s3.w);
        }
    }
    gsync(bar, tgt); tgt += NBLK;    // barrier 1: gram partials visible

    // ---------------- init: As = sum of partials, Ms = I --------------------
    {
        const float4* Gp4 = (const float4*)Gp;
        float4* As4 = (float4*)As; float4* Ms4 = (float4*)Ms;
#pragma unroll
        for (int k = 0; k < 4; ++k) {
            const int e4 = t + 256 * k;
            float4 sum = make_float4(0.f, 0.f, 0.f, 0.f);
            for (int p = 0; p < 8; ++p) {
                float4 gg = Gp4[(size_t)(b * 8 + p) * 1024 + e4];
                sum.x += gg.x; sum.y += gg.y; sum.z += gg.z; sum.w += gg.w;
            }
            As4[e4] = sum;
            float iv[4];
#pragma unroll
            for (int c = 0; c < 4; ++c) {
                const int e = 4 * e4 + c;
                iv[c] = ((e >> 6) == (e & 63)) ? 1.f : 0.f;
            }
            Ms4[e4] = make_float4(iv[0], iv[1], iv[2], iv[3]);
        }
    }

    for (int layer = 0; layer < 4; ++layer) {
        float* Hl = H + (size_t)(layer & 1) * ((size_t)BATCH * NH * 4096);  // parity dbuf
        const float* P = params + ((size_t)(layer * NH + j) * 2) * (DP * DP);
        const float* Q = P + DP * DP;
        // stage Pf^T, Qf^T (swizzled)
        {
            const int rr = t & 63, qtr = t >> 6;
#pragma unroll
            for (int k = 0; k < 16; ++k) {
                const int i = qtr * 16 + k;
                float pv = 0.f;
                if (rr < DP && i < DP) pv = P[(size_t)i * DP + rr];        // Pf[i][rr]
                else if (rr == DP && i == DP) pv = 1.f;                    // Pfull corner
                Pt[rr * 64 + 4 * ((i >> 2) ^ (rr & 15)) + (i & 3)] = pv;
                const float qv = (i < DP && rr < DP) ? Q[(size_t)i * DP + rr] : 0.f;
                Qt[rr * 64 + 4 * ((i >> 2) ^ (rr & 15)) + (i & 3)] = qv;
            }
        }
        __syncthreads();
        const int ty = t >> 4, tx = t & 15;
        // mm1: T[q][i] = sum_r G[r][q] * Pf^T[r][i]   (G symmetric)
        {
            float acc[4][4] = {};
#pragma unroll 4
            for (int r = 0; r < 64; ++r) {
                float4 av = *(const float4*)&As[r * 64 + 4 * ty];
                float4 bv = *(const float4*)&Pt[r * 64 + 4 * (tx ^ (r & 15))];
                float A[4] = {av.x, av.y, av.z, av.w}, Bb[4] = {bv.x, bv.y, bv.z, bv.w};
#pragma unroll
                for (int a = 0; a < 4; ++a)
#pragma unroll
                    for (int c = 0; c < 4; ++c) acc[a][c] += A[a] * Bb[c];
            }
#pragma unroll
            for (int a = 0; a < 4; ++a)
                *(float4*)&Tb[(4 * ty + a) * 64 + 4 * tx] =
                    make_float4(acc[a][0], acc[a][1], acc[a][2], acc[a][3]);
        }
        __syncthreads();
        // mm2: H_j[p][i] = sum_q Qf[p][q] * T[q][i], scaled by INVS -> global
        {
            float acc2[4][4] = {};
#pragma unroll 4
            for (int q = 0; q < 64; ++q) {
                float4 av = *(const float4*)&Qt[q * 64 + 4 * (ty ^ (q & 15))];
                float4 bv = *(const float4*)&Tb[q * 64 + 4 * tx];
                float A[4] = {av.x, av.y, av.z, av.w}, Bb[4] = {bv.x, bv.y, bv.z, bv.w};
#pragma unroll
                for (int a = 0; a < 4; ++a)
#pragma unroll
                    for (int c = 0; c < 4; ++c) acc2[a][c] += A[a] * Bb[c];
            }
            float* Hb = Hl + (size_t)(b * NH + j) * 4096;
#pragma unroll
            for (int a = 0; a < 4; ++a)
                *(float4*)&Hb[(4 * ty + a) * 64 + 4 * tx] =
                    make_float4(acc2[a][0] * INVS, acc2[a][1] * INVS,
                                acc2[a][2] * INVS, acc2[a][3] * INVS);
        }
        gsync(bar, tgt); tgt += NBLK;    // barriers 2-5: this layer's H visible

        // ---- redundant per-batch update (every block, local As/Ms) --------
        // W = I + sum_j H  -> Pt-space
        {
            float4* Ws4 = (float4*)Pt;
            const float4* H4 = (const float4*)Hl;
#pragma unroll
            for (int k = 0; k < 4; ++k) {
                const int e4 = t + 256 * k;
                float iv[4];
#pragma unroll
                for (int c = 0; c < 4; ++c) {
                    const int e = 4 * e4 + c;
                    iv[c] = ((e >> 6) == (e & 63)) ? 1.f : 0.f;
                }
                float4 w = make_float4(iv[0], iv[1], iv[2], iv[3]);
                for (int jj = 0; jj < 8; ++jj) {
                    float4 h = H4[(size_t)(b * 8 + jj) * 1024 + e4];
                    w.x += h.x; w.y += h.y; w.z += h.z; w.w += h.w;
                }
                Ws4[e4] = w;
            }
        }
        __syncthreads();
        float* Ws = Pt;
        if (layer < 3) {
            // Ts[q][i] = sum_r G[r][q] * W[r][i]  (G symmetric) -> Tb
            {
                float acc[4][4] = {};
#pragma unroll 4
                for (int r = 0; r < 64; ++r) {
                    float4 av = *(const float4*)&As[r * 64 + 4 * ty];
                    float4 bv = *(const float4*)&Ws[r * 64 + 4 * tx];
                    float A[4] = {av.x, av.y, av.z, av.w}, Bb[4] = {bv.x, bv.y, bv.z, bv.w};
#pragma unroll
                    for (int a = 0; a < 4; ++a)
#pragma unroll
                        for (int c = 0; c < 4; ++c) acc[a][c] += A[a] * Bb[c];
                }
#pragma unroll
                for (int a = 0; a < 4; ++a)
                    *(float4*)&Tb[(4 * ty + a) * 64 + 4 * tx] =
                        make_float4(acc[a][0], acc[a][1], acc[a][2], acc[a][3]);
            }
            __syncthreads();
            // Gnext[q][i] = sum_p W[p][q] Ts[p][i];  Mt_new[i][q] = sum_p W[p][i] Mt_old[p][q]
            float accG[4][4] = {}, accM[4][4] = {};
#pragma unroll 4
            for (int p = 0; p < 64; ++p) {
                float4 av = *(const float4*)&Ws[p * 64 + 4 * ty];
                float4 bv = *(const float4*)&Tb[p * 64 + 4 * tx];
                float4 cv = *(const float4*)&Ms[p * 64 + 4 * tx];
                float A[4] = {av.x, av.y, av.z, av.w};
                float Bb[4] = {bv.x, bv.y, bv.z, bv.w};
                float Cc[4] = {cv.x, cv.y, cv.z, cv.w};
#pragma unroll
                for (int a = 0; a < 4; ++a)
#pragma unroll
                    for (int c = 0; c < 4; ++c) {
                        accG[a][c] += A[a] * Bb[c];
                        accM[a][c] += A[a] * Cc[c];
                    }
            }
            __syncthreads();   // all As/Ms reads complete before in-place update
#pragma unroll
            for (int a = 0; a < 4; ++a) {
                *(float4*)&As[(4 * ty + a) * 64 + 4 * tx] =
                    make_float4(accG[a][0], accG[a][1], accG[a][2], accG[a][3]);
                *(float4*)&Ms[(4 * ty + a) * 64 + 4 * tx] =
                    make_float4(accM[a][0], accM[a][1], accM[a][2], accM[a][3]);
            }
            __syncthreads();
        } else {
            // final: Mf[q][i] = sum_p Mt_old[p][q] * W[p][i]  -> Tb (untransposed)
            float accM[4][4] = {};
#pragma unroll 4
            for (int p = 0; p < 64; ++p) {
                float4 av = *(const float4*)&Ms[p * 64 + 4 * ty];
                float4 bv = *(const float4*)&Ws[p * 64 + 4 * tx];
                float A[4] = {av.x, av.y, av.z, av.w}, Bb[4] = {bv.x, bv.y, bv.z, bv.w};
#pragma unroll
                for (int a = 0; a < 4; ++a)
#pragma unroll
                    for (int c = 0; c < 4; ++c) accM[a][c] += A[a] * Bb[c];
            }
            __syncthreads();   // Ms reads complete before Tb write / ZT overlay
#pragma unroll
            for (int a = 0; a < 4; ++a)
                *(float4*)&Tb[(4 * ty + a) * 64 + 4 * tx] =
                    make_float4(accM[a][0], accM[a][1], accM[a][2], accM[a][3]);
            __syncthreads();
        }
    }

    // ---------------- apply: out = Z @ Mf (Mf in Tb), rows oct=j ------------
    {
        float* ZT = (float*)sm4;            // Z^T [64][128] swizzled (As+Ms region)
        float* Ws = Tb;                      // Mf, LDS-resident
        const int ny = t & 15, ix = t >> 4;
        for (int half = 0; half < 2; ++half) {
            const size_t zbase = ((size_t)b * S + j * 256 + half * 128) * D;
            __syncthreads();   // previous ZT reads / Mf write done
#pragma unroll
            for (int k = 0; k < 8; ++k) {
                const int row = (t >> 4) + 16 * k, c4 = t & 15;
                float4 v = *(const float4*)&Z[zbase + (size_t)row * D + 4 * c4];
                float vv[4] = {v.x, v.y, v.z, v.w};
#pragma unroll
                for (int c = 0; c < 4; ++c)
                    ZT[(4 * c4 + c) * 128 + 4 * ((row >> 2) ^ c4) + (row & 3)] = vv[c];
            }
            __syncthreads();
            float acc[8][4] = {};
#pragma unroll 4
            for (int p = 0; p < 64; ++p) {
                const int f = p >> 2;
                const float* zp = &ZT[p * 128];
                float4 a0 = *(const float4*)&zp[4 * (ny ^ f)];
                float4 a1 = *(const float4*)&zp[4 * ((ny + 16) ^ f)];
                float4 wv = *(const float4*)&Ws[p * 64 + 4 * ix];
                float A[8] = {a0.x, a0.y, a0.z, a0.w, a1.x, a1.y, a1.z, a1.w};
                float Wv[4] = {wv.x, wv.y, wv.z, wv.w};
#pragma unroll
                for (int a = 0; a < 8; ++a)
#pragma unroll
                    for (int c = 0; c < 4; ++c) acc[a][c] += A[a] * Wv[c];
            }
#pragma unroll
            for (int a = 0; a < 8; ++a) {
                const int n = 4 * ny + (a & 3) + 64 * (a >> 2);
                *(float4*)&out[zbase + (size_t)n * D + 4 * ix] =
                    make_float4(acc[a][0], acc[a][1], acc[a][2], acc[a][3]);
            }
        }
    }
}

// ---------------------------------------------------------------------------
extern "C" void kernel_launch(void* const* d_in, const int* in_sizes, int n_in,
                              void* d_out, int out_size, void* d_ws, size_t ws_size,
                              hipStream_t stream) {
    const float* Z        = (const float*)d_in[0];
    const float* allparam = (const float*)d_in[1];
    float* out = (float*)d_out;

    float* Gp = (float*)d_ws;                                   // 128*16KB = 2 MB
    float* H  = Gp + (size_t)NBLK * 4096;                       // 2 x 2 MB (layer parity)
    unsigned int* bar = (unsigned int*)(H + 2 * (size_t)BATCH * NH * 4096);

    hipMemsetAsync(bar, 0, 64, stream);   // zero grid-barrier counter (capturable)
    fused_all<<<NBLK, 256, 0, stream>>>(Z, allparam, out, Gp, H, bar);
}

// Round 14
// 220.881 us; speedup vs baseline: 1.3146x; 1.0032x over previous
//
#include <hip/hip_runtime.h>

constexpr int NH = 8, DP = 63, D = 64, BATCH = 16, S = 2048;
constexpr float INVS = 1.0f / 2047.0f;
constexpr int NBLK = 256;    // one block per CU, 80 KB LDS each
constexpr int NGRP = 16, GRPSZ = 16;   // tree barrier: 16 groups of 16

// ---------------------------------------------------------------------------
// Two-level device-scope grid barrier.  Round-13 measured ~14 us/barrier with
// a SINGLE counter: 128+ serialized same-line atomic RMWs at the coherence
// point.  Tree version: blocks add to their group's counter (16 lines, 128-B
// spaced, parallel); the last arriver of each group adds to the root; all spin
// on root (relaxed) then one acquire fence.  Arrival ~16 seq RMW ≈ 2 us.
// Counters grow monotonically; round r targets grp=16r-1(old), root=16r.
// ---------------------------------------------------------------------------
__device__ __forceinline__ void gsync(unsigned int* bar, int grp, unsigned int r) {
    __syncthreads();
    if (threadIdx.x == 0) {
        unsigned int* grpc = bar + 32u * (1u + (unsigned)grp);
        unsigned int* root = bar;
        __builtin_amdgcn_fence(__ATOMIC_RELEASE, "agent");
        unsigned int old = __hip_atomic_fetch_add(grpc, 1u, __ATOMIC_RELAXED,
                                                  __HIP_MEMORY_SCOPE_AGENT);
        if (old == (unsigned)(GRPSZ * r - 1))
            __hip_atomic_fetch_add(root, 1u, __ATOMIC_RELAXED, __HIP_MEMORY_SCOPE_AGENT);
        while (__hip_atomic_load(root, __ATOMIC_RELAXED, __HIP_MEMORY_SCOPE_AGENT)
               < (unsigned)(NGRP * r))
            __builtin_amdgcn_s_sleep(2);
        __builtin_amdgcn_fence(__ATOMIC_ACQUIRE, "agent");
    }
    __syncthreads();
}

// ---------------------------------------------------------------------------
// Single fused kernel, grid 256 x 256, 5 tree barriers.
// Block (b,u): gram 128 rows (tile u); head u (u<8 only); redundant per-batch
// update (G, M^T persist in LDS); apply 128 rows (tile u).
// ---------------------------------------------------------------------------
__global__ __launch_bounds__(256) void fused_all(
    const float* __restrict__ Z, const float* __restrict__ params,
    float* __restrict__ out, float* __restrict__ Gp, float* __restrict__ H,
    unsigned int* bar) {
    __shared__ float4 sm4[5120];                  // 80 KB
    float* As = (float*)sm4;                      // G[b] persistent     (16 KB)
    float* Ms = (float*)(sm4 + 1024);             // M^T persistent      (16 KB)
    float* Pt = (float*)(sm4 + 2048);             // Pf^T slot / W slot  (16 KB)
    float* Qt = (float*)(sm4 + 3072);             // Qf^T slot           (16 KB)
    float* Tb = (float*)(sm4 + 4096);             // T slot / Mf slot    (16 KB)
    const int bid = blockIdx.x, t = threadIdx.x;
    const int b = bid >> 4, u = bid & 15;
    unsigned int r = 1;

    // ---------------- P0: Gram partial of input Z (128 rows, tile u) -------
    {
        float* ZN = (float*)(sm4 + 3072);         // [128][64] swizzled (Qt+Tb)
        const int w = t >> 6, l = t & 63, qy = l >> 3, rx = l & 7;
        float g[8][8];
#pragma unroll
        for (int a = 0; a < 8; ++a)
#pragma unroll
            for (int bb = 0; bb < 8; ++bb) g[a][bb] = 0.f;

        const int rowbase = u * 128;
#pragma unroll
        for (int k = 0; k < 8; ++k) {
            const int row = (t >> 4) + 16 * k, c4 = t & 15;
            const int grow = rowbase + row;
            float4 v = *(const float4*)&Z[((size_t)b * S + grow) * D + 4 * c4];
            if (grow == S - 1) v = make_float4(0.f, 0.f, 0.f, 0.f);  // mask last token
            *(float4*)&ZN[row * 64 + 4 * (c4 ^ ((row >> 3) & 15))] = v;
        }
        __syncthreads();
#pragma unroll 4
        for (int mi = 0; mi < 32; ++mi) {
            const int m = 32 * w + mi;
            const int f = (m >> 3) & 15;
            const float* rowp = &ZN[m * 64];
            float4 a0 = *(const float4*)&rowp[4 * (qy ^ f)];
            float4 a1 = *(const float4*)&rowp[4 * ((qy + 8) ^ f)];
            float4 b0 = *(const float4*)&rowp[4 * (rx ^ f)];
            float4 b1 = *(const float4*)&rowp[4 * ((rx + 8) ^ f)];
            float A[8]  = {a0.x, a0.y, a0.z, a0.w, a1.x, a1.y, a1.z, a1.w};
            float Bv[8] = {b0.x, b0.y, b0.z, b0.w, b1.x, b1.y, b1.z, b1.w};
#pragma unroll
            for (int a = 0; a < 8; ++a)
#pragma unroll
                for (int bb = 0; bb < 8; ++bb) g[a][bb] += A[a] * Bv[bb];
        }
        __syncthreads();   // ZN reads done before overlay
        float* part = (float*)(sm4 + w * 1024);
#pragma unroll
        for (int a = 0; a < 8; ++a) {
            const int q = 4 * qy + (a & 3) + 32 * (a >> 2);
            *(float4*)&part[q * 64 + 4 * rx]      = make_float4(g[a][0], g[a][1], g[a][2], g[a][3]);
            *(float4*)&part[q * 64 + 32 + 4 * rx] = make_float4(g[a][4], g[a][5], g[a][6], g[a][7]);
        }
        __syncthreads();
        float4* gp4 = (float4*)(Gp + (size_t)(b * 16 + u) * 4096);
#pragma unroll
        for (int k = 0; k < 4; ++k) {
            const int e4 = t + 256 * k;
            float4 s0 = sm4[e4], s1 = sm4[1024 + e4], s2 = sm4[2048 + e4], s3 = sm4[3072 + e4];
            gp4[e4] = make_float4(s0.x + s1.x + s2.x + s3.x, s0.y + s1.y + s2.y + s3.y,
                                  s0.z + s1.z + s2.z + s3.z, s0.w + s1.w + s2.w + s3.w);
        }
    }
    gsync(bar, b, r); ++r;    // barrier 1: gram partials visible

    // ---------------- init: As = sum of 16 partials, Ms = I -----------------
    {
        const float4* Gp4 = (const float4*)Gp;
        float4* As4 = (float4*)As; float4* Ms4 = (float4*)Ms;
#pragma unroll
        for (int k = 0; k < 4; ++k) {
            const int e4 = t + 256 * k;
            float4 sum = make_float4(0.f, 0.f, 0.f, 0.f);
            for (int p = 0; p < 16; ++p) {
                float4 gg = Gp4[(size_t)(b * 16 + p) * 1024 + e4];
                sum.x += gg.x; sum.y += gg.y; sum.z += gg.z; sum.w += gg.w;
            }
            As4[e4] = sum;
            float iv[4];
#pragma unroll
            for (int c = 0; c < 4; ++c) {
                const int e = 4 * e4 + c;
                iv[c] = ((e >> 6) == (e & 63)) ? 1.f : 0.f;
            }
            Ms4[e4] = make_float4(iv[0], iv[1], iv[2], iv[3]);
        }
    }

    for (int layer = 0; layer < 4; ++layer) {
        float* Hl = H + (size_t)(layer & 1) * ((size_t)BATCH * NH * 4096);  // parity dbuf
        const int ty = t >> 4, tx = t & 15;
        if (u < NH) {
            const int j = u;
            const float* P = params + ((size_t)(layer * NH + j) * 2) * (DP * DP);
            const float* Q = P + DP * DP;
            // stage Pf^T, Qf^T (swizzled)
            {
                const int rr = t & 63, qtr = t >> 6;
#pragma unroll
                for (int k = 0; k < 16; ++k) {
                    const int i = qtr * 16 + k;
                    float pv = 0.f;
                    if (rr < DP && i < DP) pv = P[(size_t)i * DP + rr];    // Pf[i][rr]
                    else if (rr == DP && i == DP) pv = 1.f;                // Pfull corner
                    Pt[rr * 64 + 4 * ((i >> 2) ^ (rr & 15)) + (i & 3)] = pv;
                    const float qv = (i < DP && rr < DP) ? Q[(size_t)i * DP + rr] : 0.f;
                    Qt[rr * 64 + 4 * ((i >> 2) ^ (rr & 15)) + (i & 3)] = qv;
                }
            }
            __syncthreads();
            // mm1: T[q][i] = sum_r G[r][q] * Pf^T[r][i]   (G symmetric)
            {
                float acc[4][4] = {};
#pragma unroll 4
                for (int rr = 0; rr < 64; ++rr) {
                    float4 av = *(const float4*)&As[rr * 64 + 4 * ty];
                    float4 bv = *(const float4*)&Pt[rr * 64 + 4 * (tx ^ (rr & 15))];
                    float A[4] = {av.x, av.y, av.z, av.w}, Bb[4] = {bv.x, bv.y, bv.z, bv.w};
#pragma unroll
                    for (int a = 0; a < 4; ++a)
#pragma unroll
                        for (int c = 0; c < 4; ++c) acc[a][c] += A[a] * Bb[c];
                }
#pragma unroll
                for (int a = 0; a < 4; ++a)
                    *(float4*)&Tb[(4 * ty + a) * 64 + 4 * tx] =
                        make_float4(acc[a][0], acc[a][1], acc[a][2], acc[a][3]);
            }
            __syncthreads();
            // mm2: H_j[p][i] = sum_q Qf[p][q] * T[q][i] * INVS -> global
            {
                float acc2[4][4] = {};
#pragma unroll 4
                for (int q = 0; q < 64; ++q) {
                    float4 av = *(const float4*)&Qt[q * 64 + 4 * (ty ^ (q & 15))];
                    float4 bv = *(const float4*)&Tb[q * 64 + 4 * tx];
                    float A[4] = {av.x, av.y, av.z, av.w}, Bb[4] = {bv.x, bv.y, bv.z, bv.w};
#pragma unroll
                    for (int a = 0; a < 4; ++a)
#pragma unroll
                        for (int c = 0; c < 4; ++c) acc2[a][c] += A[a] * Bb[c];
                }
                float* Hb = Hl + (size_t)(b * NH + j) * 4096;
#pragma unroll
                for (int a = 0; a < 4; ++a)
                    *(float4*)&Hb[(4 * ty + a) * 64 + 4 * tx] =
                        make_float4(acc2[a][0] * INVS, acc2[a][1] * INVS,
                                    acc2[a][2] * INVS, acc2[a][3] * INVS);
            }
        }
        gsync(bar, b, r); ++r;    // barriers 2-5: this layer's H visible

        // ---- redundant per-batch update (every block, local As/Ms) --------
        // W = I + sum_j H  -> Pt-space
        {
            float4* Ws4 = (float4*)Pt;
            const float4* H4 = (const float4*)Hl;
#pragma unroll
            for (int k = 0; k < 4; ++k) {
                const int e4 = t + 256 * k;
                float iv[4];
#pragma unroll
                for (int c = 0; c < 4; ++c) {
                    const int e = 4 * e4 + c;
                    iv[c] = ((e >> 6) == (e & 63)) ? 1.f : 0.f;
                }
                float4 w = make_float4(iv[0], iv[1], iv[2], iv[3]);
                for (int jj = 0; jj < 8; ++jj) {
                    float4 h = H4[(size_t)(b * 8 + jj) * 1024 + e4];
                    w.x += h.x; w.y += h.y; w.z += h.z; w.w += h.w;
                }
                Ws4[e4] = w;
            }
        }
        __syncthreads();
        const float* Ws = Pt;
        if (layer < 3) {
            // Ts[q][i] = sum_r G[r][q] * W[r][i]  (G symmetric) -> Tb
            {
                float acc[4][4] = {};
#pragma unroll 4
                for (int rr = 0; rr < 64; ++rr) {
                    float4 av = *(const float4*)&As[rr * 64 + 4 * ty];
                    float4 bv = *(const float4*)&Ws[rr * 64 + 4 * tx];
                    float A[4] = {av.x, av.y, av.z, av.w}, Bb[4] = {bv.x, bv.y, bv.z, bv.w};
#pragma unroll
                    for (int a = 0; a < 4; ++a)
#pragma unroll
                        for (int c = 0; c < 4; ++c) acc[a][c] += A[a] * Bb[c];
                }
#pragma unroll
                for (int a = 0; a < 4; ++a)
                    *(float4*)&Tb[(4 * ty + a) * 64 + 4 * tx] =
                        make_float4(acc[a][0], acc[a][1], acc[a][2], acc[a][3]);
            }
            __syncthreads();
            // Gnext[q][i] = sum_p W[p][q] Ts[p][i];  Mt_new[i][q] = sum_p W[p][i] Mt_old[p][q]
            float accG[4][4] = {}, accM[4][4] = {};
#pragma unroll 4
            for (int p = 0; p < 64; ++p) {
                float4 av = *(const float4*)&Ws[p * 64 + 4 * ty];
                float4 bv = *(const float4*)&Tb[p * 64 + 4 * tx];
                float4 cv = *(const float4*)&Ms[p * 64 + 4 * tx];
                float A[4] = {av.x, av.y, av.z, av.w};
                float Bb[4] = {bv.x, bv.y, bv.z, bv.w};
                float Cc[4] = {cv.x, cv.y, cv.z, cv.w};
#pragma unroll
                for (int a = 0; a < 4; ++a)
#pragma unroll
                    for (int c = 0; c < 4; ++c) {
                        accG[a][c] += A[a] * Bb[c];
                        accM[a][c] += A[a] * Cc[c];
                    }
            }
            __syncthreads();   // all As/Ms reads complete before in-place update
#pragma unroll
            for (int a = 0; a < 4; ++a) {
                *(float4*)&As[(4 * ty + a) * 64 + 4 * tx] =
                    make_float4(accG[a][0], accG[a][1], accG[a][2], accG[a][3]);
                *(float4*)&Ms[(4 * ty + a) * 64 + 4 * tx] =
                    make_float4(accM[a][0], accM[a][1], accM[a][2], accM[a][3]);
            }
            __syncthreads();
        } else {
            // final: Mf[q][i] = sum_p Mt_old[p][q] * W[p][i]  -> Tb (untransposed)
            float accM[4][4] = {};
#pragma unroll 4
            for (int p = 0; p < 64; ++p) {
                float4 av = *(const float4*)&Ms[p * 64 + 4 * ty];
                float4 bv = *(const float4*)&Ws[p * 64 + 4 * tx];
                float A[4] = {av.x, av.y, av.z, av.w}, Bb[4] = {bv.x, bv.y, bv.z, bv.w};
#pragma unroll
                for (int a = 0; a < 4; ++a)
#pragma unroll
                    for (int c = 0; c < 4; ++c) accM[a][c] += A[a] * Bb[c];
            }
            __syncthreads();   // Ms reads complete before Tb write / ZT overlay
#pragma unroll
            for (int a = 0; a < 4; ++a)
                *(float4*)&Tb[(4 * ty + a) * 64 + 4 * tx] =
                    make_float4(accM[a][0], accM[a][1], accM[a][2], accM[a][3]);
            __syncthreads();
        }
    }

    // ---------------- apply: out = Z @ Mf (Mf in Tb), 128 rows (tile u) ----
    {
        float* ZT = (float*)sm4;            // Z^T [64][128] swizzled (As+Ms region)
        const float* Ws = Tb;               // Mf, LDS-resident
        const int ny = t & 15, ix = t >> 4;
        const size_t zbase = ((size_t)b * S + u * 128) * D;
#pragma unroll
        for (int k = 0; k < 8; ++k) {
            const int row = (t >> 4) + 16 * k, c4 = t & 15;
            float4 v = *(const float4*)&Z[zbase + (size_t)row * D + 4 * c4];
            float vv[4] = {v.x, v.y, v.z, v.w};
#pragma unroll
            for (int c = 0; c < 4; ++c)
                ZT[(4 * c4 + c) * 128 + 4 * ((row >> 2) ^ c4) + (row & 3)] = vv[c];
        }
        __syncthreads();
        float acc[8][4] = {};
#pragma unroll 4
        for (int p = 0; p < 64; ++p) {
            const int f = p >> 2;
            const float* zp = &ZT[p * 128];
            float4 a0 = *(const float4*)&zp[4 * (ny ^ f)];
            float4 a1 = *(const float4*)&zp[4 * ((ny + 16) ^ f)];
            float4 wv = *(const float4*)&Ws[p * 64 + 4 * ix];
            float A[8] = {a0.x, a0.y, a0.z, a0.w, a1.x, a1.y, a1.z, a1.w};
            float Wv[4] = {wv.x, wv.y, wv.z, wv.w};
#pragma unroll
            for (int a = 0; a < 8; ++a)
#pragma unroll
                for (int c = 0; c < 4; ++c) acc[a][c] += A[a] * Wv[c];
        }
#pragma unroll
        for (int a = 0; a < 8; ++a) {
            const int n = 4 * ny + (a & 3) + 64 * (a >> 2);
            *(float4*)&out[zbase + (size_t)n * D + 4 * ix] =
                make_float4(acc[a][0], acc[a][1], acc[a][2], acc[a][3]);
        }
    }
}

// ---------------------------------------------------------------------------
extern "C" void kernel_launch(void* const* d_in, const int* in_sizes, int n_in,
                              void* d_out, int out_size, void* d_ws, size_t ws_size,
                              hipStream_t stream) {
    const float* Z        = (const float*)d_in[0];
    const float* allparam = (const float*)d_in[1];
    float* out = (float*)d_out;

    float* Gp = (float*)d_ws;                                   // 256*16KB = 4 MB
    float* H  = Gp + (size_t)NBLK * 4096;                       // 2 x 2 MB (layer parity)
    unsigned int* bar = (unsigned int*)(H + 2 * (size_t)BATCH * NH * 4096);

    hipMemsetAsync(bar, 0, 4096, stream);   // root + 16 group counters (128-B spaced)
    fused_all<<<NBLK, 256, 0, stream>>>(Z, allparam, out, Gp, H, bar);
}